// Round 9
// baseline (201.005 us; speedup 1.0000x reference)
//
#include <hip/hip_runtime.h>
#include <hip/hip_bf16.h>
#include <math.h>

typedef unsigned short u16;
typedef __attribute__((ext_vector_type(4))) float f32x4;
typedef __attribute__((ext_vector_type(8))) short s16x8;

#define B_    8
#define N_    4096
#define DIM_  512
#define TOK   32768     // B_*N_
#define QKVD  1536

__device__ __forceinline__ float bf2f(u16 u) {
    union { unsigned int i; float f; } x; x.i = ((unsigned int)u) << 16; return x.f;
}
__device__ __forceinline__ u16 f2bf(float f) {
    union { float f; unsigned int i; } x; x.f = f;
    unsigned int r = (x.i + 0x7fffu + ((x.i >> 16) & 1u)) >> 16;
    return (u16)r;
}

__device__ __forceinline__ void gload_lds16(const void* g, void* l) {
    __builtin_amdgcn_global_load_lds(
        (const __attribute__((address_space(1))) unsigned int*)g,
        (__attribute__((address_space(3))) unsigned int*)l, 16, 0, 0);
}

// 16B-chunk swizzle: LDS stays linear (gload_lds requirement); global source and
// ds_read both apply the same involution part^(row&7).
__device__ __forceinline__ int swz8(int row, int p) { return p ^ (row & 7); }

// ---------------- conditioning affine: cond[b][j] = silu(ce[b]) . w_cond[j] + b_cond[j]
__global__ void k_cond(const float* __restrict__ ce, const float* __restrict__ w_cond,
                       const float* __restrict__ b_cond, float* __restrict__ cond)
{
    __shared__ float s[512];
    int jt = blockIdx.x, b = blockIdx.y;
    int tid = threadIdx.x, wid = tid >> 6, lane = tid & 63;
    for (int i = tid; i < 512; i += 256) {
        float v = ce[b * 512 + i];
        s[i] = v / (1.f + __expf(-v));
    }
    __syncthreads();
#pragma unroll
    for (int jj = 0; jj < 4; ++jj) {
        int j = jt * 16 + wid * 4 + jj;
        const float4* w4 = (const float4*)(w_cond + (size_t)j * 512);
        float4 a = w4[lane * 2], c = w4[lane * 2 + 1];
        float acc = a.x*s[lane*8+0] + a.y*s[lane*8+1] + a.z*s[lane*8+2] + a.w*s[lane*8+3]
                  + c.x*s[lane*8+4] + c.y*s[lane*8+5] + c.z*s[lane*8+6] + c.w*s[lane*8+7];
#pragma unroll
        for (int d = 1; d < 64; d <<= 1) acc += __shfl_xor(acc, d, 64);
        if (lane == 0) cond[b * 1024 + j] = acc + b_cond[j];
    }
}

// ---------------- w_qkv fp32 -> bf16
__global__ void k_w2bf(const float* __restrict__ w, u16* __restrict__ wb)
{
    int i = (blockIdx.x * 256 + threadIdx.x) * 4;
    float4 v = *(const float4*)&w[i];
    ushort4 o; o.x = f2bf(v.x); o.y = f2bf(v.y); o.z = f2bf(v.z); o.w = f2bf(v.w);
    *(ushort4*)&wb[i] = o;
}

// ---------------- pre-LN + modulation -> xm bf16 ; one wave per token
__global__ void k_lnmod(const float* __restrict__ x, const float* __restrict__ cond,
                        const float* __restrict__ gamma, u16* __restrict__ xm)
{
    int wave = threadIdx.x >> 6, lane = threadIdx.x & 63;
    size_t t = (size_t)blockIdx.x * 4 + wave;
    const float* xr = x + t * 512;
    float4 v0 = ((const float4*)xr)[lane * 2];
    float4 v1 = ((const float4*)xr)[lane * 2 + 1];
    float s  = v0.x+v0.y+v0.z+v0.w + v1.x+v1.y+v1.z+v1.w;
    float ss = v0.x*v0.x+v0.y*v0.y+v0.z*v0.z+v0.w*v0.w
             + v1.x*v1.x+v1.y*v1.y+v1.z*v1.z+v1.w*v1.w;
#pragma unroll
    for (int m = 1; m < 64; m <<= 1) { s += __shfl_xor(s, m, 64); ss += __shfl_xor(ss, m, 64); }
    float mu = s * (1.f/512.f);
    float var = ss * (1.f/512.f) - mu * mu;
    float rs = rsqrtf(var + 1e-5f);
    int b = (int)(t >> 12);
    const float* cb = cond + b * 1024;
    float4 g0  = ((const float4*)gamma)[lane*2],     g1  = ((const float4*)gamma)[lane*2+1];
    float4 sc0 = ((const float4*)cb)[lane*2],        sc1 = ((const float4*)cb)[lane*2+1];
    float4 sh0 = ((const float4*)(cb+512))[lane*2],  sh1 = ((const float4*)(cb+512))[lane*2+1];
    ushort4 o0, o1;
    o0.x = f2bf(((v0.x-mu)*rs*g0.x)*(1.f+sc0.x) + sh0.x);
    o0.y = f2bf(((v0.y-mu)*rs*g0.y)*(1.f+sc0.y) + sh0.y);
    o0.z = f2bf(((v0.z-mu)*rs*g0.z)*(1.f+sc0.z) + sh0.z);
    o0.w = f2bf(((v0.w-mu)*rs*g0.w)*(1.f+sc0.w) + sh0.w);
    o1.x = f2bf(((v1.x-mu)*rs*g1.x)*(1.f+sc1.x) + sh1.x);
    o1.y = f2bf(((v1.y-mu)*rs*g1.y)*(1.f+sc1.y) + sh1.y);
    o1.z = f2bf(((v1.z-mu)*rs*g1.z)*(1.f+sc1.z) + sh1.z);
    o1.w = f2bf(((v1.w-mu)*rs*g1.w)*(1.f+sc1.w) + sh1.w);
    ushort4* orow = (ushort4*)(xm + t * 512);
    orow[lane * 2] = o0; orow[lane * 2 + 1] = o1;
}

// ---------------- qkv GEMM (bf16 MFMA, 128x128 tile, BK=64, swizzled LDS)
// fused epilogue: bn<4 -> q feature-softmax (*1/8); bn>=4 -> plain store (k,v).
__global__ __launch_bounds__(256, 3)
void k_gemmqkv(const u16* __restrict__ A,
               const u16* __restrict__ Bm,
               u16* __restrict__ Out)
{
    __shared__ __align__(16) u16 As[128 * 64];
    __shared__ __align__(16) u16 Bs[128 * 64];
    // XCD-aware swizzle: 3072 blocks, 8 XCDs -> each XCD gets 32 contiguous bm panels
    int sid = (blockIdx.x & 7) * 384 + (blockIdx.x >> 3);
    int bn = sid % 12, bm = sid / 12;
    int m0 = bm * 128, n0 = bn * 128;
    int tid = threadIdx.x;
    int wid = tid >> 6, lane = tid & 63;
    int wr = (wid >> 1) * 64, wc = (wid & 1) * 64;
    int fr = lane & 15, fc = lane >> 4;

    f32x4 acc[4][4];
#pragma unroll
    for (int m = 0; m < 4; ++m)
#pragma unroll
        for (int n = 0; n < 4; ++n) acc[m][n] = (f32x4)0.f;

    for (int k0 = 0; k0 < 512; k0 += 64) {
#pragma unroll
        for (int i = 0; i < 4; ++i) {
            int c = tid + i * 256;
            int row = c >> 3, p = c & 7, gp = swz8(row, p);
            gload_lds16(A  + (size_t)(m0 + row) * 512 + k0 + gp * 8, &As[c * 8]);
            gload_lds16(Bm + (size_t)(n0 + row) * 512 + k0 + gp * 8, &Bs[c * 8]);
        }
        __syncthreads();
#pragma unroll
        for (int kk = 0; kk < 2; ++kk) {
            s16x8 af[4], bfr[4];
            int q = kk * 4 + fc;
#pragma unroll
            for (int m = 0; m < 4; ++m) {
                int row = wr + m * 16 + fr;
                af[m] = *(const s16x8*)&As[(row * 8 + swz8(row, q)) * 8];
            }
#pragma unroll
            for (int n = 0; n < 4; ++n) {
                int row = wc + n * 16 + fr;
                bfr[n] = *(const s16x8*)&Bs[(row * 8 + swz8(row, q)) * 8];
            }
#pragma unroll
            for (int m = 0; m < 4; ++m)
#pragma unroll
                for (int n = 0; n < 4; ++n)
                    acc[m][n] = __builtin_amdgcn_mfma_f32_16x16x32_bf16(af[m], bfr[n], acc[m][n], 0, 0, 0);
        }
        __syncthreads();
    }

    int rbase = m0 + wr + fc * 4;
    int cbase = n0 + wc + fr;

    if (bn < 4) {
        // q: softmax over the wave's 64 cols (= one head), scale 1/8
#pragma unroll
        for (int m = 0; m < 4; ++m) {
            float v[4][4];
#pragma unroll
            for (int n = 0; n < 4; ++n)
#pragma unroll
                for (int r = 0; r < 4; ++r) v[n][r] = acc[m][n][r];
#pragma unroll
            for (int r = 0; r < 4; ++r) {
                float mx = fmaxf(fmaxf(v[0][r], v[1][r]), fmaxf(v[2][r], v[3][r]));
#pragma unroll
                for (int d = 1; d < 16; d <<= 1) mx = fmaxf(mx, __shfl_xor(mx, d, 64));
                float e0 = __expf(v[0][r]-mx), e1 = __expf(v[1][r]-mx);
                float e2 = __expf(v[2][r]-mx), e3 = __expf(v[3][r]-mx);
                float sm = e0 + e1 + e2 + e3;
#pragma unroll
                for (int d = 1; d < 16; d <<= 1) sm += __shfl_xor(sm, d, 64);
                float rv = 0.125f / sm;
                v[0][r] = e0*rv; v[1][r] = e1*rv; v[2][r] = e2*rv; v[3][r] = e3*rv;
            }
#pragma unroll
            for (int n = 0; n < 4; ++n)
#pragma unroll
                for (int r = 0; r < 4; ++r)
                    Out[(size_t)(rbase + m*16 + r) * QKVD + (cbase + n*16)] = f2bf(v[n][r]);
        }
    } else {
#pragma unroll
        for (int m = 0; m < 4; ++m)
#pragma unroll
            for (int n = 0; n < 4; ++n)
#pragma unroll
                for (int r = 0; r < 4; ++r)
                    Out[(size_t)(rbase + m*16 + r) * QKVD + (cbase + n*16)] = f2bf(acc[m][n][r]);
    }
}

// ---------------- context (MFMA): ctxp[b,h,slot,d,e] partials of
// sum_n exp(k[n,d]) * v[n,e]  (no max shift), plus ksum partials
// ksump[b,h,slot,d] = sum_n exp(k[n,d]). 16 slots per (b,h); normalization
// happens in k_wc. grid (8,8,8): block nc covers rows nc*512..+511.
__global__ __launch_bounds__(256, 2)
void k_ctx(const u16* __restrict__ qkv, float* __restrict__ ctxp, float* __restrict__ ksump)
{
    __shared__ __align__(16) u16 sA[4][64 * 40];
    __shared__ __align__(16) u16 sB[4][64 * 40];
    __shared__ float scr[2][4096];
    __shared__ float kscr[2][64];
    int nc = blockIdx.x, h = blockIdx.y, b = blockIdx.z;
    int wid = threadIdx.x >> 6, lane = threadIdx.x & 63;
    u16* A  = sA[wid];
    u16* Bt = sB[wid];
    int fr = lane & 15, fk = (lane >> 4) * 8;
    f32x4 acc[4][4];
#pragma unroll
    for (int m = 0; m < 4; ++m)
#pragma unroll
        for (int n = 0; n < 4; ++n) acc[m][n] = (f32x4)0.f;
    float ksl = 0.f;

    size_t rowbase = (size_t)b * 4096 + nc * 512 + wid * 32;
    const u16* kp = qkv + rowbase * QKVD + 512 + h * 64 + lane;
    const u16* vp = kp + 512;

    for (int it = 0; it < 4; ++it) {
        const u16* kq = kp + (size_t)it * 128 * QKVD;
        const u16* vq = vp + (size_t)it * 128 * QKVD;
        unsigned int pk[16], pv[16];
#pragma unroll
        for (int j = 0; j < 16; ++j) {
            float a0 = __expf(bf2f(kq[(size_t)(2*j)   * QKVD]));
            float a1 = __expf(bf2f(kq[(size_t)(2*j+1) * QKVD]));
            ksl += a0 + a1;
            pk[j] = (unsigned)f2bf(a0) | ((unsigned)f2bf(a1) << 16);
            float b0 = bf2f(vq[(size_t)(2*j)   * QKVD]);
            float b1 = bf2f(vq[(size_t)(2*j+1) * QKVD]);
            pv[j] = (unsigned)f2bf(b0) | ((unsigned)f2bf(b1) << 16);
        }
#pragma unroll
        for (int j = 0; j < 4; ++j) {
            *(uint4*)&A [lane * 40 + j * 8] = *(uint4*)&pk[j * 4];
            *(uint4*)&Bt[lane * 40 + j * 8] = *(uint4*)&pv[j * 4];
        }
        s16x8 af[4], bfr[4];
#pragma unroll
        for (int m = 0; m < 4; ++m) af[m]  = *(const s16x8*)&A [(m * 16 + fr) * 40 + fk];
#pragma unroll
        for (int n = 0; n < 4; ++n) bfr[n] = *(const s16x8*)&Bt[(n * 16 + fr) * 40 + fk];
#pragma unroll
        for (int m = 0; m < 4; ++m)
#pragma unroll
            for (int n = 0; n < 4; ++n)
                acc[m][n] = __builtin_amdgcn_mfma_f32_16x16x32_bf16(af[m], bfr[n], acc[m][n], 0, 0, 0);
    }

    __syncthreads();
    int rbase = (lane >> 4) * 4, cbase = lane & 15;
    if (wid >= 2) {
#pragma unroll
        for (int m = 0; m < 4; ++m)
#pragma unroll
            for (int n = 0; n < 4; ++n)
#pragma unroll
                for (int r = 0; r < 4; ++r)
                    scr[wid - 2][(m * 16 + rbase + r) * 64 + n * 16 + cbase] = acc[m][n][r];
        kscr[wid - 2][lane] = ksl;
    }
    __syncthreads();
    if (wid < 2) {
        float* cp = ctxp + (((size_t)(b * 8 + h) * 16) + nc * 2 + wid) * 4096;
#pragma unroll
        for (int m = 0; m < 4; ++m)
#pragma unroll
            for (int n = 0; n < 4; ++n)
#pragma unroll
                for (int r = 0; r < 4; ++r) {
                    int idx = (m * 16 + rbase + r) * 64 + n * 16 + cbase;
                    cp[idx] = acc[m][n][r] + scr[wid][idx];
                }
        ksump[(((size_t)(b * 8 + h) * 16) + nc * 2 + wid) * 64 + lane] = ksl + kscr[wid][lane];
    }
}

// ---------------- Wc[b][j][h*64+d] = sum_e (ctx[b,h,d,e]/ksum[b,h,d]) * w_out[j][h*64+e]
// grid (8h, 8b); jt loop inside so ctxp slice is read exactly once per block.
__global__ void k_wc(const float* __restrict__ ctxp, const float* __restrict__ ksump,
                     const float* __restrict__ w_out, u16* __restrict__ Wc)
{
    __shared__ float csh[64 * 65];
    __shared__ float wsh[64 * 65];
    __shared__ float inv[64];
    int h = blockIdx.x, b = blockIdx.y;
    int tid = threadIdx.x;
    const float* cp = ctxp + (size_t)(b * 8 + h) * 16 * 4096;
    const float* kp = ksump + (size_t)(b * 8 + h) * 16 * 64;
    if (tid < 64) {
        float s = 0.f;
#pragma unroll
        for (int sl = 0; sl < 16; ++sl) s += kp[sl * 64 + tid];
        inv[tid] = 1.f / s;
    }
    for (int idx = tid; idx < 4096; idx += 256) {
        float sum = 0.f;
#pragma unroll
        for (int sl = 0; sl < 16; ++sl) sum += cp[sl * 4096 + idx];
        csh[(idx >> 6) * 65 + (idx & 63)] = sum;
    }
    __syncthreads();
    for (int idx = tid; idx < 4096; idx += 256)
        csh[(idx >> 6) * 65 + (idx & 63)] *= inv[idx >> 6];
    __syncthreads();

    int j0 = (tid >> 4) * 4, d0 = (tid & 15) * 4;
    for (int jt = 0; jt < 8; ++jt) {
        for (int idx = tid; idx < 4096; idx += 256) {
            int d = idx >> 6, e = idx & 63;
            wsh[d * 65 + e] = w_out[(size_t)(jt * 64 + d) * 512 + h * 64 + e];
        }
        __syncthreads();
        float acc[4][4] = {};
        for (int e = 0; e < 64; ++e) {
            float wv[4], cv[4];
#pragma unroll
            for (int i = 0; i < 4; ++i) wv[i] = wsh[(j0 + i) * 65 + e];
#pragma unroll
            for (int j = 0; j < 4; ++j) cv[j] = csh[(d0 + j) * 65 + e];
#pragma unroll
            for (int i = 0; i < 4; ++i)
#pragma unroll
                for (int j = 0; j < 4; ++j) acc[i][j] += wv[i] * cv[j];
        }
#pragma unroll
        for (int i = 0; i < 4; ++i)
#pragma unroll
            for (int j = 0; j < 4; ++j)
                Wc[((size_t)b * 512 + jt * 64 + j0 + i) * 512 + h * 64 + d0 + j] = f2bf(acc[i][j]);
        __syncthreads();
    }
}

// ---------------- GEMM2 + final LayerNorm fused. BM=64, BN=512 (full rows),
// BK=64, 8 waves (1Mx8N), swizzled LDS, 76KB LDS -> 2 blocks/CU, f32 output.
__global__ __launch_bounds__(512, 2)
void k_g2ln(const u16* __restrict__ Aq, const u16* __restrict__ Wc,
            const float* __restrict__ gamma, float* __restrict__ out)
{
    __shared__ __align__(16) u16 As[64 * 64];      // 8 KB
    __shared__ __align__(16) u16 Bs[512 * 64];     // 64 KB
    __shared__ float rsum[64][8], rssq[64][8];     // 4 KB
    int bm = blockIdx.x;
    int m0 = bm * 64;
    int b = m0 >> 12;
    const u16* Bp = Wc + (size_t)b * 512 * 512;
    int tid = threadIdx.x;
    int wn = tid >> 6, lane = tid & 63;            // wave owns cols [wn*64, +64)
    int fr = lane & 15, fc = lane >> 4;

    f32x4 acc[4][4];
#pragma unroll
    for (int m = 0; m < 4; ++m)
#pragma unroll
        for (int n = 0; n < 4; ++n) acc[m][n] = (f32x4)0.f;

    for (int k0 = 0; k0 < 512; k0 += 64) {
        {
            int c = tid;                            // 512 chunks = 64 rows x 8 parts
            int row = c >> 3, p = c & 7, gp = swz8(row, p);
            gload_lds16(Aq + (size_t)(m0 + row) * QKVD + k0 + gp * 8, &As[c * 8]);
        }
#pragma unroll
        for (int i = 0; i < 8; ++i) {
            int c = tid + i * 512;
            int col = c >> 3, p = c & 7, gp = swz8(col, p);
            gload_lds16(Bp + (size_t)col * 512 + k0 + gp * 8, &Bs[c * 8]);
        }
        __syncthreads();
#pragma unroll
        for (int kk = 0; kk < 2; ++kk) {
            int q = kk * 4 + fc;
            s16x8 af[4], bfr[4];
#pragma unroll
            for (int m = 0; m < 4; ++m) {
                int row = m * 16 + fr;
                af[m] = *(const s16x8*)&As[(row * 8 + swz8(row, q)) * 8];
            }
#pragma unroll
            for (int n = 0; n < 4; ++n) {
                int col = wn * 64 + n * 16 + fr;
                bfr[n] = *(const s16x8*)&Bs[(col * 8 + swz8(col, q)) * 8];
            }
#pragma unroll
            for (int m = 0; m < 4; ++m)
#pragma unroll
                for (int n = 0; n < 4; ++n)
                    acc[m][n] = __builtin_amdgcn_mfma_f32_16x16x32_bf16(af[m], bfr[n], acc[m][n], 0, 0, 0);
        }
        __syncthreads();
    }

    // per-row LN stats: each wave reduces its 64-col slice, cross-wave via LDS
#pragma unroll
    for (int m = 0; m < 4; ++m)
#pragma unroll
        for (int r = 0; r < 4; ++r) {
            float s = 0.f, ss = 0.f;
#pragma unroll
            for (int n = 0; n < 4; ++n) { float v = acc[m][n][r]; s += v; ss += v * v; }
#pragma unroll
            for (int d = 1; d < 16; d <<= 1) { s += __shfl_xor(s, d, 64); ss += __shfl_xor(ss, d, 64); }
            if ((lane & 15) == 0) {
                int row = m * 16 + fc * 4 + r;
                rsum[row][wn] = s; rssq[row][wn] = ss;
            }
        }
    __syncthreads();

    float g[4];
#pragma unroll
    for (int n = 0; n < 4; ++n) g[n] = gamma[wn * 64 + n * 16 + fr];

#pragma unroll
    for (int m = 0; m < 4; ++m)
#pragma unroll
        for (int r = 0; r < 4; ++r) {
            int row = m * 16 + fc * 4 + r;
            float s  = 0.f, ss = 0.f;
#pragma unroll
            for (int w = 0; w < 8; ++w) { s += rsum[row][w]; ss += rssq[row][w]; }
            float mu = s * (1.f/512.f);
            float var = ss * (1.f/512.f) - mu * mu;
            float rs = rsqrtf(var + 1e-5f);
            float* orow = out + (size_t)(m0 + row) * 512;
#pragma unroll
            for (int n = 0; n < 4; ++n)
                orow[wn * 64 + n * 16 + fr] = (acc[m][n][r] - mu) * rs * g[n];
        }
}

extern "C" void kernel_launch(void* const* d_in, const int* in_sizes, int n_in,
                              void* d_out, int out_size, void* d_ws, size_t ws_size,
                              hipStream_t stream)
{
    const float* x        = (const float*)d_in[0];
    const float* ce       = (const float*)d_in[1];
    const float* gamma_in = (const float*)d_in[2];
    const float* w_cond   = (const float*)d_in[3];
    const float* b_cond   = (const float*)d_in[4];
    const float* w_qkv    = (const float*)d_in[5];
    const float* w_out    = (const float*)d_in[6];
    const float* gamma_out= (const float*)d_in[7];
    float* out = (float*)d_out;

    char* ws = (char*)d_ws;
    size_t o = 0;
    auto take = [&](size_t bytes) -> char* {
        char* p = ws + o; o += (bytes + 255) & ~(size_t)255; return p;
    };
    float* cond  = (float*)take(8 * 1024 * 4);
    u16*   wqkvb = (u16*)  take((size_t)1536 * 512 * 2);
    float* ksump = (float*)take((size_t)64 * 16 * 64 * 4);    // [b*h][slot16][64]
    float* ctxp  = (float*)take((size_t)64 * 16 * 4096 * 4);  // [b*h][slot16][64][64]
    u16*   Wc    = (u16*)  take((size_t)8 * 512 * 512 * 2);
    u16*   xm    = (u16*)  take((size_t)TOK * 512 * 2);
    u16*   qkv   = (u16*)  take((size_t)TOK * QKVD * 2);

    k_cond   <<<dim3(64, 8), 256, 0, stream>>>(ce, w_cond, b_cond, cond);
    k_w2bf   <<<768, 256, 0, stream>>>(w_qkv, wqkvb);
    k_lnmod  <<<8192, 256, 0, stream>>>(x, cond, gamma_in, xm);
    k_gemmqkv<<<3072, 256, 0, stream>>>(xm, wqkvb, qkv);
    k_ctx    <<<dim3(8, 8, 8), 256, 0, stream>>>(qkv, ctxp, ksump);
    k_wc     <<<dim3(8, 8), 256, 0, stream>>>(ctxp, ksump, w_out, Wc);
    k_g2ln   <<<512, 512, 0, stream>>>(qkv, Wc, gamma_out, out);
}

// Round 10
// 165.158 us; speedup vs baseline: 1.2170x; 1.2170x over previous
//
#include <hip/hip_runtime.h>
#include <hip/hip_bf16.h>
#include <math.h>

typedef unsigned short u16;
typedef __attribute__((ext_vector_type(4))) float f32x4;
typedef __attribute__((ext_vector_type(8))) short s16x8;

#define B_    8
#define N_    4096
#define DIM_  512
#define TOK   32768     // B_*N_
#define QKVD  1536

__device__ __forceinline__ float bf2f(u16 u) {
    union { unsigned int i; float f; } x; x.i = ((unsigned int)u) << 16; return x.f;
}
__device__ __forceinline__ u16 f2bf(float f) {
    union { float f; unsigned int i; } x; x.f = f;
    unsigned int r = (x.i + 0x7fffu + ((x.i >> 16) & 1u)) >> 16;
    return (u16)r;
}

__device__ __forceinline__ void gload_lds16(const void* g, void* l) {
    __builtin_amdgcn_global_load_lds(
        (const __attribute__((address_space(1))) unsigned int*)g,
        (__attribute__((address_space(3))) unsigned int*)l, 16, 0, 0);
}

// 16B-chunk swizzle: LDS stays linear (gload_lds requirement); global source and
// ds_read both apply the same involution part^(row&7).
__device__ __forceinline__ int swz8(int row, int p) { return p ^ (row & 7); }

// ---------------- conditioning affine: cond[b][j] = silu(ce[b]) . w_cond[j] + b_cond[j]
__global__ void k_cond(const float* __restrict__ ce, const float* __restrict__ w_cond,
                       const float* __restrict__ b_cond, float* __restrict__ cond)
{
    __shared__ float s[512];
    int jt = blockIdx.x, b = blockIdx.y;
    int tid = threadIdx.x, wid = tid >> 6, lane = tid & 63;
    for (int i = tid; i < 512; i += 256) {
        float v = ce[b * 512 + i];
        s[i] = v / (1.f + __expf(-v));
    }
    __syncthreads();
#pragma unroll
    for (int jj = 0; jj < 4; ++jj) {
        int j = jt * 16 + wid * 4 + jj;
        const float4* w4 = (const float4*)(w_cond + (size_t)j * 512);
        float4 a = w4[lane * 2], c = w4[lane * 2 + 1];
        float acc = a.x*s[lane*8+0] + a.y*s[lane*8+1] + a.z*s[lane*8+2] + a.w*s[lane*8+3]
                  + c.x*s[lane*8+4] + c.y*s[lane*8+5] + c.z*s[lane*8+6] + c.w*s[lane*8+7];
#pragma unroll
        for (int d = 1; d < 64; d <<= 1) acc += __shfl_xor(acc, d, 64);
        if (lane == 0) cond[b * 1024 + j] = acc + b_cond[j];
    }
}

// ---------------- w_qkv fp32 -> bf16
__global__ void k_w2bf(const float* __restrict__ w, u16* __restrict__ wb)
{
    int i = (blockIdx.x * 256 + threadIdx.x) * 4;
    float4 v = *(const float4*)&w[i];
    ushort4 o; o.x = f2bf(v.x); o.y = f2bf(v.y); o.z = f2bf(v.z); o.w = f2bf(v.w);
    *(ushort4*)&wb[i] = o;
}

// ---------------- pre-LN + modulation -> xm bf16 ; one wave per token
__global__ void k_lnmod(const float* __restrict__ x, const float* __restrict__ cond,
                        const float* __restrict__ gamma, u16* __restrict__ xm)
{
    int wave = threadIdx.x >> 6, lane = threadIdx.x & 63;
    size_t t = (size_t)blockIdx.x * 4 + wave;
    const float* xr = x + t * 512;
    float4 v0 = ((const float4*)xr)[lane * 2];
    float4 v1 = ((const float4*)xr)[lane * 2 + 1];
    float s  = v0.x+v0.y+v0.z+v0.w + v1.x+v1.y+v1.z+v1.w;
    float ss = v0.x*v0.x+v0.y*v0.y+v0.z*v0.z+v0.w*v0.w
             + v1.x*v1.x+v1.y*v1.y+v1.z*v1.z+v1.w*v1.w;
#pragma unroll
    for (int m = 1; m < 64; m <<= 1) { s += __shfl_xor(s, m, 64); ss += __shfl_xor(ss, m, 64); }
    float mu = s * (1.f/512.f);
    float var = ss * (1.f/512.f) - mu * mu;
    float rs = rsqrtf(var + 1e-5f);
    int b = (int)(t >> 12);
    const float* cb = cond + b * 1024;
    float4 g0  = ((const float4*)gamma)[lane*2],     g1  = ((const float4*)gamma)[lane*2+1];
    float4 sc0 = ((const float4*)cb)[lane*2],        sc1 = ((const float4*)cb)[lane*2+1];
    float4 sh0 = ((const float4*)(cb+512))[lane*2],  sh1 = ((const float4*)(cb+512))[lane*2+1];
    ushort4 o0, o1;
    o0.x = f2bf(((v0.x-mu)*rs*g0.x)*(1.f+sc0.x) + sh0.x);
    o0.y = f2bf(((v0.y-mu)*rs*g0.y)*(1.f+sc0.y) + sh0.y);
    o0.z = f2bf(((v0.z-mu)*rs*g0.z)*(1.f+sc0.z) + sh0.z);
    o0.w = f2bf(((v0.w-mu)*rs*g0.w)*(1.f+sc0.w) + sh0.w);
    o1.x = f2bf(((v1.x-mu)*rs*g1.x)*(1.f+sc1.x) + sh1.x);
    o1.y = f2bf(((v1.y-mu)*rs*g1.y)*(1.f+sc1.y) + sh1.y);
    o1.z = f2bf(((v1.z-mu)*rs*g1.z)*(1.f+sc1.z) + sh1.z);
    o1.w = f2bf(((v1.w-mu)*rs*g1.w)*(1.f+sc1.w) + sh1.w);
    ushort4* orow = (ushort4*)(xm + t * 512);
    orow[lane * 2] = o0; orow[lane * 2 + 1] = o1;
}

// ---------------- qkv GEMM (bf16 MFMA, 128x128 tile, BK=64, swizzled LDS)
// fused epilogue: bn<4 -> q feature-softmax (*1/8); bn>=4 -> plain store (k,v).
__global__ __launch_bounds__(256, 3)
void k_gemmqkv(const u16* __restrict__ A,
               const u16* __restrict__ Bm,
               u16* __restrict__ Out)
{
    __shared__ __align__(16) u16 As[128 * 64];
    __shared__ __align__(16) u16 Bs[128 * 64];
    // XCD-aware swizzle: 3072 blocks, 8 XCDs -> each XCD gets 32 contiguous bm panels
    int sid = (blockIdx.x & 7) * 384 + (blockIdx.x >> 3);
    int bn = sid % 12, bm = sid / 12;
    int m0 = bm * 128, n0 = bn * 128;
    int tid = threadIdx.x;
    int wid = tid >> 6, lane = tid & 63;
    int wr = (wid >> 1) * 64, wc = (wid & 1) * 64;
    int fr = lane & 15, fc = lane >> 4;

    f32x4 acc[4][4];
#pragma unroll
    for (int m = 0; m < 4; ++m)
#pragma unroll
        for (int n = 0; n < 4; ++n) acc[m][n] = (f32x4)0.f;

    for (int k0 = 0; k0 < 512; k0 += 64) {
#pragma unroll
        for (int i = 0; i < 4; ++i) {
            int c = tid + i * 256;
            int row = c >> 3, p = c & 7, gp = swz8(row, p);
            gload_lds16(A  + (size_t)(m0 + row) * 512 + k0 + gp * 8, &As[c * 8]);
            gload_lds16(Bm + (size_t)(n0 + row) * 512 + k0 + gp * 8, &Bs[c * 8]);
        }
        __syncthreads();
#pragma unroll
        for (int kk = 0; kk < 2; ++kk) {
            s16x8 af[4], bfr[4];
            int q = kk * 4 + fc;
#pragma unroll
            for (int m = 0; m < 4; ++m) {
                int row = wr + m * 16 + fr;
                af[m] = *(const s16x8*)&As[(row * 8 + swz8(row, q)) * 8];
            }
#pragma unroll
            for (int n = 0; n < 4; ++n) {
                int row = wc + n * 16 + fr;
                bfr[n] = *(const s16x8*)&Bs[(row * 8 + swz8(row, q)) * 8];
            }
#pragma unroll
            for (int m = 0; m < 4; ++m)
#pragma unroll
                for (int n = 0; n < 4; ++n)
                    acc[m][n] = __builtin_amdgcn_mfma_f32_16x16x32_bf16(af[m], bfr[n], acc[m][n], 0, 0, 0);
        }
        __syncthreads();
    }

    int rbase = m0 + wr + fc * 4;
    int cbase = n0 + wc + fr;

    if (bn < 4) {
        // q: softmax over the wave's 64 cols (= one head), scale 1/8
#pragma unroll
        for (int m = 0; m < 4; ++m) {
            float v[4][4];
#pragma unroll
            for (int n = 0; n < 4; ++n)
#pragma unroll
                for (int r = 0; r < 4; ++r) v[n][r] = acc[m][n][r];
#pragma unroll
            for (int r = 0; r < 4; ++r) {
                float mx = fmaxf(fmaxf(v[0][r], v[1][r]), fmaxf(v[2][r], v[3][r]));
#pragma unroll
                for (int d = 1; d < 16; d <<= 1) mx = fmaxf(mx, __shfl_xor(mx, d, 64));
                float e0 = __expf(v[0][r]-mx), e1 = __expf(v[1][r]-mx);
                float e2 = __expf(v[2][r]-mx), e3 = __expf(v[3][r]-mx);
                float sm = e0 + e1 + e2 + e3;
#pragma unroll
                for (int d = 1; d < 16; d <<= 1) sm += __shfl_xor(sm, d, 64);
                float rv = 0.125f / sm;
                v[0][r] = e0*rv; v[1][r] = e1*rv; v[2][r] = e2*rv; v[3][r] = e3*rv;
            }
#pragma unroll
            for (int n = 0; n < 4; ++n)
#pragma unroll
                for (int r = 0; r < 4; ++r)
                    Out[(size_t)(rbase + m*16 + r) * QKVD + (cbase + n*16)] = f2bf(v[n][r]);
        }
    } else {
#pragma unroll
        for (int m = 0; m < 4; ++m)
#pragma unroll
            for (int n = 0; n < 4; ++n)
#pragma unroll
                for (int r = 0; r < 4; ++r)
                    Out[(size_t)(rbase + m*16 + r) * QKVD + (cbase + n*16)] = f2bf(acc[m][n][r]);
    }
}

// ---------------- context (MFMA): ctxp[b,h,slot,d,e] partials of
// sum_n exp(k[n,d]) * v[n,e]  (no max shift), plus ksum partials
// ksump[b,h,slot,d] = sum_n exp(k[n,d]). 16 slots per (b,h).
__global__ __launch_bounds__(256, 2)
void k_ctx(const u16* __restrict__ qkv, float* __restrict__ ctxp, float* __restrict__ ksump)
{
    __shared__ __align__(16) u16 sA[4][64 * 40];
    __shared__ __align__(16) u16 sB[4][64 * 40];
    __shared__ float scr[2][4096];
    __shared__ float kscr[2][64];
    int nc = blockIdx.x, h = blockIdx.y, b = blockIdx.z;
    int wid = threadIdx.x >> 6, lane = threadIdx.x & 63;
    u16* A  = sA[wid];
    u16* Bt = sB[wid];
    int fr = lane & 15, fk = (lane >> 4) * 8;
    f32x4 acc[4][4];
#pragma unroll
    for (int m = 0; m < 4; ++m)
#pragma unroll
        for (int n = 0; n < 4; ++n) acc[m][n] = (f32x4)0.f;
    float ksl = 0.f;

    size_t rowbase = (size_t)b * 4096 + nc * 512 + wid * 32;
    const u16* kp = qkv + rowbase * QKVD + 512 + h * 64 + lane;
    const u16* vp = kp + 512;

    for (int it = 0; it < 4; ++it) {
        const u16* kq = kp + (size_t)it * 128 * QKVD;
        const u16* vq = vp + (size_t)it * 128 * QKVD;
        unsigned int pk[16], pv[16];
#pragma unroll
        for (int j = 0; j < 16; ++j) {
            float a0 = __expf(bf2f(kq[(size_t)(2*j)   * QKVD]));
            float a1 = __expf(bf2f(kq[(size_t)(2*j+1) * QKVD]));
            ksl += a0 + a1;
            pk[j] = (unsigned)f2bf(a0) | ((unsigned)f2bf(a1) << 16);
            float b0 = bf2f(vq[(size_t)(2*j)   * QKVD]);
            float b1 = bf2f(vq[(size_t)(2*j+1) * QKVD]);
            pv[j] = (unsigned)f2bf(b0) | ((unsigned)f2bf(b1) << 16);
        }
#pragma unroll
        for (int j = 0; j < 4; ++j) {
            *(uint4*)&A [lane * 40 + j * 8] = *(uint4*)&pk[j * 4];
            *(uint4*)&Bt[lane * 40 + j * 8] = *(uint4*)&pv[j * 4];
        }
        s16x8 af[4], bfr[4];
#pragma unroll
        for (int m = 0; m < 4; ++m) af[m]  = *(const s16x8*)&A [(m * 16 + fr) * 40 + fk];
#pragma unroll
        for (int n = 0; n < 4; ++n) bfr[n] = *(const s16x8*)&Bt[(n * 16 + fr) * 40 + fk];
#pragma unroll
        for (int m = 0; m < 4; ++m)
#pragma unroll
            for (int n = 0; n < 4; ++n)
                acc[m][n] = __builtin_amdgcn_mfma_f32_16x16x32_bf16(af[m], bfr[n], acc[m][n], 0, 0, 0);
    }

    __syncthreads();
    int rbase = (lane >> 4) * 4, cbase = lane & 15;
    if (wid >= 2) {
#pragma unroll
        for (int m = 0; m < 4; ++m)
#pragma unroll
            for (int n = 0; n < 4; ++n)
#pragma unroll
                for (int r = 0; r < 4; ++r)
                    scr[wid - 2][(m * 16 + rbase + r) * 64 + n * 16 + cbase] = acc[m][n][r];
        kscr[wid - 2][lane] = ksl;
    }
    __syncthreads();
    if (wid < 2) {
        float* cp = ctxp + (((size_t)(b * 8 + h) * 16) + nc * 2 + wid) * 4096;
#pragma unroll
        for (int m = 0; m < 4; ++m)
#pragma unroll
            for (int n = 0; n < 4; ++n)
#pragma unroll
                for (int r = 0; r < 4; ++r) {
                    int idx = (m * 16 + rbase + r) * 64 + n * 16 + cbase;
                    cp[idx] = acc[m][n][r] + scr[wid][idx];
                }
        ksump[(((size_t)(b * 8 + h) * 16) + nc * 2 + wid) * 64 + lane] = ksl + kscr[wid][lane];
    }
}

// ---------------- sum 16 slots + normalize: ctxs[b,h,d,e] = (sum_sl ctxp)/(sum_sl ksump[d])
__global__ void k_csum(const float* __restrict__ ctxp, const float* __restrict__ ksump,
                       float* __restrict__ ctxs)
{
    __shared__ float inv[64];
    int h = blockIdx.x, b = blockIdx.y;
    int tid = threadIdx.x;
    const float* cp = ctxp + (size_t)(b * 8 + h) * 16 * 4096;
    const float* kp = ksump + (size_t)(b * 8 + h) * 16 * 64;
    if (tid < 64) {
        float s = 0.f;
#pragma unroll
        for (int sl = 0; sl < 16; ++sl) s += kp[sl * 64 + tid];
        inv[tid] = 1.f / s;
    }
    __syncthreads();
    float* op = ctxs + (size_t)(b * 8 + h) * 4096;
    for (int idx = tid; idx < 4096; idx += 256) {
        float sum = 0.f;
#pragma unroll
        for (int sl = 0; sl < 16; ++sl) sum += cp[sl * 4096 + idx];
        op[idx] = sum * inv[idx >> 6];
    }
}

// ---------------- Wc[b][j][h*64+d] = sum_e ctxs[b,h,d,e] * w_out[j][h*64+e]
__global__ void k_wc(const float* __restrict__ ctxs, const float* __restrict__ w_out,
                     u16* __restrict__ Wc)
{
    __shared__ float csh[64 * 65];
    __shared__ float wsh[64 * 65];
    int jt = blockIdx.x, h = blockIdx.y, b = blockIdx.z;
    int tid = threadIdx.x;
    const float* cp = ctxs + (size_t)(b * 8 + h) * 4096;
    for (int idx = tid; idx < 4096; idx += 256) {
        int d = idx >> 6, e = idx & 63;
        csh[d * 65 + e] = cp[idx];
        wsh[d * 65 + e] = w_out[(size_t)(jt * 64 + d) * 512 + h * 64 + e];
    }
    __syncthreads();
    int j0 = (tid >> 4) * 4, d0 = (tid & 15) * 4;
    float acc[4][4] = {};
    for (int e = 0; e < 64; ++e) {
        float wv[4], cv[4];
#pragma unroll
        for (int i = 0; i < 4; ++i) wv[i] = wsh[(j0 + i) * 65 + e];
#pragma unroll
        for (int j = 0; j < 4; ++j) cv[j] = csh[(d0 + j) * 65 + e];
#pragma unroll
        for (int i = 0; i < 4; ++i)
#pragma unroll
            for (int j = 0; j < 4; ++j) acc[i][j] += wv[i] * cv[j];
    }
#pragma unroll
    for (int i = 0; i < 4; ++i)
#pragma unroll
        for (int j = 0; j < 4; ++j)
            Wc[((size_t)b * 512 + jt * 64 + j0 + i) * 512 + h * 64 + d0 + j] = f2bf(acc[i][j]);
}

// ---------------- GEMM2 + final LayerNorm fused. BM=64, BN=512 (full rows),
// BK=64, 8 waves (1Mx8N), swizzled LDS, 76KB LDS -> 2 blocks/CU, f32 output.
__global__ __launch_bounds__(512, 2)
void k_g2ln(const u16* __restrict__ Aq, const u16* __restrict__ Wc,
            const float* __restrict__ gamma, float* __restrict__ out)
{
    __shared__ __align__(16) u16 As[64 * 64];      // 8 KB
    __shared__ __align__(16) u16 Bs[512 * 64];     // 64 KB
    __shared__ float rsum[64][8], rssq[64][8];     // 4 KB
    int bm = blockIdx.x;
    int m0 = bm * 64;
    int b = m0 >> 12;
    const u16* Bp = Wc + (size_t)b * 512 * 512;
    int tid = threadIdx.x;
    int wn = tid >> 6, lane = tid & 63;            // wave owns cols [wn*64, +64)
    int fr = lane & 15, fc = lane >> 4;

    f32x4 acc[4][4];
#pragma unroll
    for (int m = 0; m < 4; ++m)
#pragma unroll
        for (int n = 0; n < 4; ++n) acc[m][n] = (f32x4)0.f;

    for (int k0 = 0; k0 < 512; k0 += 64) {
        {
            int c = tid;                            // 512 chunks = 64 rows x 8 parts
            int row = c >> 3, p = c & 7, gp = swz8(row, p);
            gload_lds16(Aq + (size_t)(m0 + row) * QKVD + k0 + gp * 8, &As[c * 8]);
        }
#pragma unroll
        for (int i = 0; i < 8; ++i) {
            int c = tid + i * 512;
            int col = c >> 3, p = c & 7, gp = swz8(col, p);
            gload_lds16(Bp + (size_t)col * 512 + k0 + gp * 8, &Bs[c * 8]);
        }
        __syncthreads();
#pragma unroll
        for (int kk = 0; kk < 2; ++kk) {
            int q = kk * 4 + fc;
            s16x8 af[4], bfr[4];
#pragma unroll
            for (int m = 0; m < 4; ++m) {
                int row = m * 16 + fr;
                af[m] = *(const s16x8*)&As[(row * 8 + swz8(row, q)) * 8];
            }
#pragma unroll
            for (int n = 0; n < 4; ++n) {
                int col = wn * 64 + n * 16 + fr;
                bfr[n] = *(const s16x8*)&Bs[(col * 8 + swz8(col, q)) * 8];
            }
#pragma unroll
            for (int m = 0; m < 4; ++m)
#pragma unroll
                for (int n = 0; n < 4; ++n)
                    acc[m][n] = __builtin_amdgcn_mfma_f32_16x16x32_bf16(af[m], bfr[n], acc[m][n], 0, 0, 0);
        }
        __syncthreads();
    }

    // per-row LN stats: each wave reduces its 64-col slice, cross-wave via LDS
#pragma unroll
    for (int m = 0; m < 4; ++m)
#pragma unroll
        for (int r = 0; r < 4; ++r) {
            float s = 0.f, ss = 0.f;
#pragma unroll
            for (int n = 0; n < 4; ++n) { float v = acc[m][n][r]; s += v; ss += v * v; }
#pragma unroll
            for (int d = 1; d < 16; d <<= 1) { s += __shfl_xor(s, d, 64); ss += __shfl_xor(ss, d, 64); }
            if ((lane & 15) == 0) {
                int row = m * 16 + fc * 4 + r;
                rsum[row][wn] = s; rssq[row][wn] = ss;
            }
        }
    __syncthreads();

    float g[4];
#pragma unroll
    for (int n = 0; n < 4; ++n) g[n] = gamma[wn * 64 + n * 16 + fr];

#pragma unroll
    for (int m = 0; m < 4; ++m)
#pragma unroll
        for (int r = 0; r < 4; ++r) {
            int row = m * 16 + fc * 4 + r;
            float s  = 0.f, ss = 0.f;
#pragma unroll
            for (int w = 0; w < 8; ++w) { s += rsum[row][w]; ss += rssq[row][w]; }
            float mu = s * (1.f/512.f);
            float var = ss * (1.f/512.f) - mu * mu;
            float rs = rsqrtf(var + 1e-5f);
            float* orow = out + (size_t)(m0 + row) * 512;
#pragma unroll
            for (int n = 0; n < 4; ++n)
                orow[wn * 64 + n * 16 + fr] = (acc[m][n][r] - mu) * rs * g[n];
        }
}

extern "C" void kernel_launch(void* const* d_in, const int* in_sizes, int n_in,
                              void* d_out, int out_size, void* d_ws, size_t ws_size,
                              hipStream_t stream)
{
    const float* x        = (const float*)d_in[0];
    const float* ce       = (const float*)d_in[1];
    const float* gamma_in = (const float*)d_in[2];
    const float* w_cond   = (const float*)d_in[3];
    const float* b_cond   = (const float*)d_in[4];
    const float* w_qkv    = (const float*)d_in[5];
    const float* w_out    = (const float*)d_in[6];
    const float* gamma_out= (const float*)d_in[7];
    float* out = (float*)d_out;

    char* ws = (char*)d_ws;
    size_t o = 0;
    auto take = [&](size_t bytes) -> char* {
        char* p = ws + o; o += (bytes + 255) & ~(size_t)255; return p;
    };
    float* cond  = (float*)take(8 * 1024 * 4);
    u16*   wqkvb = (u16*)  take((size_t)1536 * 512 * 2);
    float* ksump = (float*)take((size_t)64 * 16 * 64 * 4);    // [b*h][slot16][64]
    float* ctxp  = (float*)take((size_t)64 * 16 * 4096 * 4);  // [b*h][slot16][64][64]
    float* ctxs  = (float*)take((size_t)64 * 4096 * 4);       // [b*h][64][64]
    u16*   Wc    = (u16*)  take((size_t)8 * 512 * 512 * 2);
    u16*   xm    = (u16*)  take((size_t)TOK * 512 * 2);
    u16*   qkv   = (u16*)  take((size_t)TOK * QKVD * 2);

    k_cond   <<<dim3(64, 8), 256, 0, stream>>>(ce, w_cond, b_cond, cond);
    k_w2bf   <<<768, 256, 0, stream>>>(w_qkv, wqkvb);
    k_lnmod  <<<8192, 256, 0, stream>>>(x, cond, gamma_in, xm);
    k_gemmqkv<<<3072, 256, 0, stream>>>(xm, wqkvb, qkv);
    k_ctx    <<<dim3(8, 8, 8), 256, 0, stream>>>(qkv, ctxp, ksump);
    k_csum   <<<dim3(8, 8), 256, 0, stream>>>(ctxp, ksump, ctxs);
    k_wc     <<<dim3(8, 8, 8), 256, 0, stream>>>(ctxs, w_out, Wc);
    k_g2ln   <<<512, 512, 0, stream>>>(qkv, Wc, gamma_out, out);
}